// Round 10
// baseline (673.968 us; speedup 1.0000x reference)
//
#include <hip/hip_runtime.h>
#include <hip/hip_bf16.h>
#include <cstdint>
#include <cstddef>

// Problem constants
constexpr int T = 8;
constexpr int C = 256;     // feature channels = GEMM K
constexpr int N = 4096;    // H*W pixels per frame
constexpr float TEMP_INV = 14.285714285714286f;  // 1/0.07
constexpr float EPS = 1e-8f;

typedef __bf16 bf16;
typedef __bf16 bf16x8 __attribute__((ext_vector_type(8)));
typedef float floatx4 __attribute__((ext_vector_type(4)));

// ---------------------------------------------------------------------------
// async global->LDS, 16B per lane, wave-uniform LDS base + lane*16
__device__ __forceinline__ void async_copy16(const bf16* g, bf16* l) {
    __builtin_amdgcn_global_load_lds((const __attribute__((address_space(1))) void*)g,
                                     (__attribute__((address_space(3))) void*)l,
                                     16, 0, 0);
}

// ---------------------------------------------------------------------------
// Normalize + in-block frame dice + labels + rank compaction + swizzled
// scatter (R9's version, passed twice). fg rank r -> fpack row r; bg rank r
// -> fpack row 4095-r. Counters zeroed by hipMemsetAsync before this launch.
__global__ __launch_bounds__(256, 4) void normalize_kernel(const float* __restrict__ feat,
                                                           const float* __restrict__ cur,
                                                           const float* __restrict__ hist,
                                                           float* __restrict__ out_labels,
                                                           float* __restrict__ negbuf,
                                                           float* __restrict__ posc,
                                                           bf16* __restrict__ fpack,
                                                           int* __restrict__ nfg,
                                                           int* __restrict__ nbg) {
    __shared__ bf16 tile[64 * 258];    // [n][c] true chunk order, pad 258
    __shared__ float partial[256];
    __shared__ float rnorm_s[64];
    __shared__ int rowpk_s[64];
    __shared__ float dice[12];
    __shared__ float flag_s;
    int t = blockIdx.x >> 6;
    int n0 = (blockIdx.x & 63) * 64;
    int tid = threadIdx.x;
    int lane63 = tid & 63;
    int w = tid >> 6;

    const float* fb = feat + (size_t)t * C * N;
    float ss = 0.f;
    #pragma unroll 16
    for (int it = 0; it < 64; ++it) {
        int c = w * 64 + it;
        float v = fb[(size_t)c * N + n0 + lane63];
        ss += v * v;
        tile[lane63 * 258 + c] = (bf16)v;
    }
    partial[tid] = ss;

    // frame dice (redundant per block, deterministic)
    const float* cb_ = cur + (size_t)t * N;
    const float* hb_ = hist + (size_t)t * N;
    float s1 = 0.f, sc = 0.f, sh = 0.f;
    #pragma unroll 4
    for (int i = tid; i < N; i += 256) {
        float c = cb_[i], h = hb_[i];
        float cb = c > 0.5f ? 1.f : 0.f;
        float hb = h > 0.5f ? 1.f : 0.f;
        s1 += cb * hb; sc += cb; sh += hb;
    }
    for (int o = 32; o > 0; o >>= 1) {
        s1 += __shfl_down(s1, o);
        sc += __shfl_down(sc, o);
        sh += __shfl_down(sh, o);
    }
    if (lane63 == 0) { dice[w] = s1; dice[4 + w] = sc; dice[8 + w] = sh; }
    __syncthreads();
    if (tid == 0) {
        float e1 = dice[0] + dice[1] + dice[2] + dice[3];
        float scs = dice[4] + dice[5] + dice[6] + dice[7];
        float shs = dice[8] + dice[9] + dice[10] + dice[11];
        float e2 = scs + shs;
        float m1 = (2.f * e1 + EPS) / (e2 + EPS);
        float m2 = (e1 + EPS) / (e2 - e1 + EPS);
        float dev = 1.f - 0.5f * (m1 + m2);
        flag_s = (dev <= 0.0f) ? 1.f : 0.f;
    }
    __syncthreads();

    if (tid < 64) {                    // wave 0: labels + ranks for 64 pixels
        float s = partial[tid] + partial[tid + 64] + partial[tid + 128] + partial[tid + 192];
        float r = 1.f / fmaxf(sqrtf(s), 1e-12f);
        rnorm_s[tid] = r;
        int gi = t * N + n0 + tid;
        float lab = (flag_s != 0.f) ? cur[gi] : hist[gi];
        out_labels[gi] = lab;
        bool fg = lab > 0.5f;
        unsigned long long b = __ballot(fg);
        unsigned long long lowmask = (tid == 63) ? 0x7fffffffffffffffull
                                                 : ((1ull << tid) - 1ull);
        int rank_fg = __popcll(b & lowmask);
        int rank_bg = __popcll((~b) & lowmask);
        int cnt = __popcll(b);
        int base_fg = 0, base_bg = 0;
        if (tid == 0) {
            base_fg = atomicAdd(&nfg[t], cnt);
            base_bg = atomicAdd(&nbg[t], 64 - cnt);
        }
        base_fg = __shfl(base_fg, 0);
        base_bg = __shfl(base_bg, 0);
        int rank = fg ? (base_fg + rank_fg) : (base_bg + rank_bg);
        int rowpk = fg ? rank : (4095 - rank);
        rowpk_s[tid] = rowpk;
        if (fg) {
            posc[t * N + rank] = s * r * r;
            negbuf[t * N + rank] = 0.f;
        }
    }
    __syncthreads();
    bf16* fp = fpack + (size_t)t * N * C;
    #pragma unroll
    for (int it = 0; it < 8; ++it) {
        int l = it * 256 + tid;        // 16B-chunk index within tile, 0..2047
        int n = l >> 5;                // tile pixel
        int c8 = l & 31;               // true chunk 0..31
        int rp = rowpk_s[n];
        int slot = (c8 & ~7) | ((c8 & 7) ^ (rp & 7));   // XOR-swizzled store pos
        float r = rnorm_s[n];
        bf16x8 vin = *(const bf16x8*)&tile[n * 258 + c8 * 8];
        bf16x8 vo;
        for (int j = 0; j < 8; ++j) vo[j] = (bf16)((float)vin[j] * r);
        *(bf16x8*)(fp + (size_t)rp * C + slot * 8) = vo;
    }
}

// ---------------------------------------------------------------------------
// sim GEMM + exp + bg row-sum: EXACT R6 structure (proven 57 us) -- 128x128
// tile, 4 waves, single-buffer LDS, global_load_lds w16, XOR swizzle,
// lb(256,3), static 8192 grid, frame = blockIdx&7 (XCD pin). Only additions:
// descending-bg row addressing (R8/R9-verified) and the fused loss tail.
__global__ __launch_bounds__(256, 3) void sim_kernel(const bf16* __restrict__ fpack,
                                                     const int* __restrict__ nfg,
                                                     const int* __restrict__ nbg,
                                                     float* __restrict__ neg,
                                                     const float* __restrict__ posc,
                                                     int* __restrict__ donecnt,
                                                     float* __restrict__ out_loss) {
    __shared__ bf16 a_lds[128 * 64];
    __shared__ bf16 b_lds[128 * 64];
    __shared__ float red[256];
    __shared__ int last_s;

    int tid = threadIdx.x;
    int t = blockIdx.x & 7;            // frame -> XCD pin
    int tile = blockIdx.x >> 3;        // 0..1023
    int rowbase = (tile >> 5) * 128;
    int colbase = (tile & 31) * 128;
    int nfgt = nfg[t];
    int nbgt = nbg[t];

    if (rowbase < nfgt && colbase < nbgt) {     // block-uniform
        int lane = tid & 63;
        int w = tid >> 6;
        int lrow = lane >> 3;
        int lchunk = lane & 7;
        int quad = lane >> 4;
        int r0w = (w & 1) * 64;
        int c0w = (w >> 1) * 64;
        const bf16* fb = fpack + (size_t)t * N * C;

        floatx4 acc[4][4];
        #pragma unroll
        for (int i = 0; i < 4; ++i)
            #pragma unroll
            for (int j = 0; j < 4; ++j)
                acc[i][j] = (floatx4){0.f, 0.f, 0.f, 0.f};

        for (int ks = 0; ks < 4; ++ks) {
            int k0 = ks * 64;
            __syncthreads();
            for (int s = 0; s < 4; ++s) {
                int q = w * 4 + s;                        // 0..15
                int ra = rowbase + q * 8 + lrow;          // fg rank (ascending)
                int rb = 4095 - (colbase + q * 8 + lrow); // bg rank (descending)
                async_copy16(fb + (size_t)ra * C + k0 + lchunk * 8, &a_lds[q * 512]);
                async_copy16(fb + (size_t)rb * C + k0 + lchunk * 8, &b_lds[q * 512]);
            }
            __syncthreads();
            for (int kk = 0; kk < 64; kk += 32) {
                int chread = (kk >> 3) + quad;            // true sub-chunk wanted
                bf16x8 af[4], bfr[4];
                #pragma unroll
                for (int i = 0; i < 4; ++i) {
                    int r = r0w + 16 * i + (lane & 15);
                    int chs = chread ^ (r & 7);
                    af[i] = *(const bf16x8*)&a_lds[r * 64 + chs * 8];
                }
                #pragma unroll
                for (int j = 0; j < 4; ++j) {
                    int cl = c0w + 16 * j + (lane & 15);
                    int chs = chread ^ 7 ^ (cl & 7);      // bg stored descending
                    bfr[j] = *(const bf16x8*)&b_lds[cl * 64 + chs * 8];
                }
                #pragma unroll
                for (int i = 0; i < 4; ++i)
                    #pragma unroll
                    for (int j = 0; j < 4; ++j)
                        acc[i][j] = __builtin_amdgcn_mfma_f32_16x16x32_bf16(af[i], bfr[j], acc[i][j], 0, 0, 0);
            }
        }

        // epilogue: exp + col-mask + row reduce + atomics
        bool okc[4];
        #pragma unroll
        for (int j = 0; j < 4; ++j)
            okc[j] = (colbase + c0w + 16 * j + (lane & 15)) < nbgt;
        #pragma unroll
        for (int i = 0; i < 4; ++i) {
            #pragma unroll
            for (int reg = 0; reg < 4; ++reg) {
                float msum = 0.f;
                #pragma unroll
                for (int j = 0; j < 4; ++j) {
                    float e = __expf(acc[i][j][reg] * TEMP_INV);
                    msum += okc[j] ? e : 0.f;
                }
                msum += __shfl_xor(msum, 1);
                msum += __shfl_xor(msum, 2);
                msum += __shfl_xor(msum, 4);
                msum += __shfl_xor(msum, 8);
                if ((lane & 15) == 0) {
                    int row = rowbase + r0w + 16 * i + quad * 4 + reg;
                    if (row < nfgt) atomicAdd(&neg[t * N + row], msum);
                }
            }
        }
    }

    // completion handshake; last block computes the final loss scalar
    __syncthreads();
    __threadfence();                   // release our neg atomics
    if (tid == 0) last_s = (atomicAdd(donecnt, 1) == (int)gridDim.x - 1) ? 1 : 0;
    __syncthreads();
    if (last_s) {
        float fsum = 0.f, vsum = 0.f;  // meaningful on tid 0 only
        for (int tt = 0; tt < T; ++tt) {
            int nf = nfg[tt];
            float s = 0.f;
            for (int k = tid; k < nf; k += 256) {
                float pos = __expf(posc[tt * N + k] * TEMP_INV);
                float ng = atomicAdd(&neg[tt * N + k], 0.f);   // coherent read
                s += logf((pos + ng + EPS) / pos);
            }
            red[tid] = s;
            __syncthreads();
            for (int o = 128; o > 0; o >>= 1) {
                if (tid < o) red[tid] += red[tid + o];
                __syncthreads();
            }
            if (tid == 0) {
                float valid = (nf > 0 && nbg[tt] > 0) ? 1.f : 0.f;
                fsum += valid * (red[0] / fmaxf((float)nf, 1.f));
                vsum += valid;
            }
            __syncthreads();
        }
        if (tid == 0)
            out_loss[0] = (vsum > 0.f) ? fsum / fmaxf(vsum, 1.f) : 0.f;
    }
}

// ---------------------------------------------------------------------------
extern "C" void kernel_launch(void* const* d_in, const int* in_sizes, int n_in,
                              void* d_out, int out_size, void* d_ws, size_t ws_size,
                              hipStream_t stream) {
    const float* cur  = (const float*)d_in[0];
    const float* hist = (const float*)d_in[1];
    const float* feat = (const float*)d_in[2];
    float* out = (float*)d_out;   // labels[32768] ++ loss[1]

    char* ws = (char*)d_ws;
    bf16*  fpack   = (bf16*)ws;                           // 8*4096*256 bf16 = 16 MiB
    size_t off = (size_t)T * N * C * sizeof(bf16);
    float* negbuf  = (float*)(ws + off);  off += (size_t)T * N * 4;
    float* posc    = (float*)(ws + off);  off += (size_t)T * N * 4;
    int*   nfg     = (int*)(ws + off);                    // nfg[8] nbg[8] donecnt[1]
    int*   nbg     = nfg + 8;
    int*   donecnt = nbg + 8;

    hipMemsetAsync(nfg, 0, 128, stream);                  // zero counters (capturable)
    normalize_kernel<<<512, 256, 0, stream>>>(feat, cur, hist, out, negbuf, posc, fpack, nfg, nbg);
    sim_kernel<<<8192, 256, 0, stream>>>(fpack, nfg, nbg, negbuf, posc, donecnt, out + 32768);
}

// Round 11
// 171.286 us; speedup vs baseline: 3.9347x; 3.9347x over previous
//
#include <hip/hip_runtime.h>
#include <hip/hip_bf16.h>
#include <cstdint>
#include <cstddef>

// Problem constants
constexpr int T = 8;
constexpr int C = 256;     // feature channels = GEMM K
constexpr int N = 4096;    // H*W pixels per frame
constexpr float TEMP_INV = 14.285714285714286f;  // 1/0.07
constexpr float EPS = 1e-8f;

typedef __bf16 bf16;
typedef __bf16 bf16x8 __attribute__((ext_vector_type(8)));
typedef float floatx4 __attribute__((ext_vector_type(4)));

// ---------------------------------------------------------------------------
// async global->LDS, 16B per lane, wave-uniform LDS base + lane*16
__device__ __forceinline__ void async_copy16(const bf16* g, bf16* l) {
    __builtin_amdgcn_global_load_lds((const __attribute__((address_space(1))) void*)g,
                                     (__attribute__((address_space(3))) void*)l,
                                     16, 0, 0);
}

// ---------------------------------------------------------------------------
// Normalize + in-block frame dice + labels + rank compaction + swizzled
// scatter. v2: 32-pixel tiles (1024 blocks = 4/CU), float4 global loads
// (16 B/lane, 8 VMEM instr/thread vs 64 scalar).
// fg rank r -> fpack row r; bg rank r -> fpack row 4095-r.
// Counters zeroed by hipMemsetAsync before this launch.
__global__ __launch_bounds__(256, 4) void normalize_kernel(const float* __restrict__ feat,
                                                           const float* __restrict__ cur,
                                                           const float* __restrict__ hist,
                                                           float* __restrict__ out_labels,
                                                           float* __restrict__ negbuf,
                                                           float* __restrict__ posc,
                                                           bf16* __restrict__ fpack,
                                                           int* __restrict__ nfg,
                                                           int* __restrict__ nbg) {
    __shared__ bf16 tile[32 * 258];    // [p][ch], pad 258 -> conflict-free chunk reads
    __shared__ float partw[4][32];     // per-wave 4-px-group partial sumsq
    __shared__ float rnorm_s[32];
    __shared__ int rowpk_s[32];
    __shared__ float dice[12];
    __shared__ float flag_s;
    int t = blockIdx.x >> 7;           // 8 frames x 128 tiles
    int n0 = (blockIdx.x & 127) * 32;  // 32 pixels per block
    int tid = threadIdx.x;
    int lane63 = tid & 63;
    int w = tid >> 6;

    // ---- vectorized transpose load: thread covers pixel group pxg (4 px),
    //      8 channels (it*32 + tid>>3)
    const float* fb = feat + (size_t)t * C * N;
    int pxg = tid & 7;
    int chb = tid >> 3;                // 0..31
    float ssx = 0.f, ssy = 0.f, ssz = 0.f, ssw = 0.f;
    #pragma unroll
    for (int it = 0; it < 8; ++it) {
        int ch = it * 32 + chb;
        float4 v = *(const float4*)(fb + (size_t)ch * N + n0 + pxg * 4);
        ssx += v.x * v.x; ssy += v.y * v.y; ssz += v.z * v.z; ssw += v.w * v.w;
        bf16* dst = &tile[(pxg * 4) * 258 + ch];
        dst[0]   = (bf16)v.x;
        dst[258] = (bf16)v.y;
        dst[516] = (bf16)v.z;
        dst[774] = (bf16)v.w;
    }
    // reduce sumsq over the 8 lanes per wave sharing pxg (xor 8,16,32)
    #pragma unroll
    for (int o = 8; o < 64; o <<= 1) {
        ssx += __shfl_xor(ssx, o);
        ssy += __shfl_xor(ssy, o);
        ssz += __shfl_xor(ssz, o);
        ssw += __shfl_xor(ssw, o);
    }
    if (lane63 < 8) {
        partw[w][lane63 * 4 + 0] = ssx;
        partw[w][lane63 * 4 + 1] = ssy;
        partw[w][lane63 * 4 + 2] = ssz;
        partw[w][lane63 * 4 + 3] = ssw;
    }

    // ---- frame dice (redundant per block, deterministic)
    const float* cb_ = cur + (size_t)t * N;
    const float* hb_ = hist + (size_t)t * N;
    float s1 = 0.f, sc = 0.f, sh = 0.f;
    #pragma unroll 4
    for (int i = tid; i < N; i += 256) {
        float c = cb_[i], h = hb_[i];
        float cb = c > 0.5f ? 1.f : 0.f;
        float hb = h > 0.5f ? 1.f : 0.f;
        s1 += cb * hb; sc += cb; sh += hb;
    }
    for (int o = 32; o > 0; o >>= 1) {
        s1 += __shfl_down(s1, o);
        sc += __shfl_down(sc, o);
        sh += __shfl_down(sh, o);
    }
    if (lane63 == 0) { dice[w] = s1; dice[4 + w] = sc; dice[8 + w] = sh; }
    __syncthreads();
    if (tid == 0) {
        float e1 = dice[0] + dice[1] + dice[2] + dice[3];
        float scs = dice[4] + dice[5] + dice[6] + dice[7];
        float shs = dice[8] + dice[9] + dice[10] + dice[11];
        float e2 = scs + shs;
        float m1 = (2.f * e1 + EPS) / (e2 + EPS);
        float m2 = (e1 + EPS) / (e2 - e1 + EPS);
        float dev = 1.f - 0.5f * (m1 + m2);
        flag_s = (dev <= 0.0f) ? 1.f : 0.f;
    }
    __syncthreads();

    if (tid < 32) {                    // pixel tid: norm + label + rank
        float s = partw[0][tid] + partw[1][tid] + partw[2][tid] + partw[3][tid];
        float r = 1.f / fmaxf(sqrtf(s), 1e-12f);
        rnorm_s[tid] = r;
        int gi = t * N + n0 + tid;
        float lab = (flag_s != 0.f) ? cur[gi] : hist[gi];
        out_labels[gi] = lab;
        bool fg = lab > 0.5f;
        unsigned long long b = __ballot(fg);   // inactive lanes contribute 0
        unsigned long long lowmask = (1ull << tid) - 1ull;
        int rank_fg = __popcll(b & lowmask);
        int rank_bg = __popcll((~b) & lowmask & 0xffffffffull);
        int cnt = __popcll(b);
        int base_fg = 0, base_bg = 0;
        if (tid == 0) {
            base_fg = atomicAdd(&nfg[t], cnt);
            base_bg = atomicAdd(&nbg[t], 32 - cnt);
        }
        base_fg = __shfl(base_fg, 0);
        base_bg = __shfl(base_bg, 0);
        int rank = fg ? (base_fg + rank_fg) : (base_bg + rank_bg);
        int rowpk = fg ? rank : (4095 - rank);
        rowpk_s[tid] = rowpk;
        if (fg) {
            posc[t * N + rank] = s * r * r;
            negbuf[t * N + rank] = 0.f;
        }
    }
    __syncthreads();

    // ---- swizzled scatter: 32 px x 32 chunks = 1024 slots, 4 iterations
    bf16* fp = fpack + (size_t)t * N * C;
    #pragma unroll
    for (int it = 0; it < 4; ++it) {
        int l = it * 256 + tid;
        int n = l >> 5;                // tile pixel 0..31
        int c8 = l & 31;               // true chunk 0..31
        int rp = rowpk_s[n];
        int slot = (c8 & ~7) | ((c8 & 7) ^ (rp & 7));   // XOR-swizzled store pos
        float r = rnorm_s[n];
        bf16x8 vin = *(const bf16x8*)&tile[n * 258 + c8 * 8];
        bf16x8 vo;
        for (int j = 0; j < 8; ++j) vo[j] = (bf16)((float)vin[j] * r);
        *(bf16x8*)(fp + (size_t)rp * C + slot * 8) = vo;
    }
}

// ---------------------------------------------------------------------------
// sim GEMM + exp + bg row-sum: R6/R10 proven body, NO fused tail (R10 lesson:
// per-block __threadfence = device fence per wave = ~500 us across the grid).
// 128x128 tile, 4 waves, single-buffer LDS, global_load_lds w16, XOR swizzle,
// lb(256,3), static 8192 grid, frame = blockIdx&7 (XCD pin).
__global__ __launch_bounds__(256, 3) void sim_kernel(const bf16* __restrict__ fpack,
                                                     const int* __restrict__ nfg,
                                                     const int* __restrict__ nbg,
                                                     float* __restrict__ neg) {
    __shared__ bf16 a_lds[128 * 64];
    __shared__ bf16 b_lds[128 * 64];

    int tid = threadIdx.x;
    int t = blockIdx.x & 7;            // frame -> XCD pin
    int tile = blockIdx.x >> 3;        // 0..1023
    int rowbase = (tile >> 5) * 128;
    int colbase = (tile & 31) * 128;
    int nfgt = nfg[t];
    int nbgt = nbg[t];
    if (rowbase >= nfgt || colbase >= nbgt) return;

    int lane = tid & 63;
    int w = tid >> 6;
    int lrow = lane >> 3;
    int lchunk = lane & 7;
    int quad = lane >> 4;
    int r0w = (w & 1) * 64;
    int c0w = (w >> 1) * 64;
    const bf16* fb = fpack + (size_t)t * N * C;

    floatx4 acc[4][4];
    #pragma unroll
    for (int i = 0; i < 4; ++i)
        #pragma unroll
        for (int j = 0; j < 4; ++j)
            acc[i][j] = (floatx4){0.f, 0.f, 0.f, 0.f};

    for (int ks = 0; ks < 4; ++ks) {
        int k0 = ks * 64;
        __syncthreads();
        for (int s = 0; s < 4; ++s) {
            int q = w * 4 + s;                        // 0..15
            int ra = rowbase + q * 8 + lrow;          // fg rank (ascending)
            int rb = 4095 - (colbase + q * 8 + lrow); // bg rank (descending)
            async_copy16(fb + (size_t)ra * C + k0 + lchunk * 8, &a_lds[q * 512]);
            async_copy16(fb + (size_t)rb * C + k0 + lchunk * 8, &b_lds[q * 512]);
        }
        __syncthreads();
        for (int kk = 0; kk < 64; kk += 32) {
            int chread = (kk >> 3) + quad;            // true sub-chunk wanted
            bf16x8 af[4], bfr[4];
            #pragma unroll
            for (int i = 0; i < 4; ++i) {
                int r = r0w + 16 * i + (lane & 15);
                int chs = chread ^ (r & 7);
                af[i] = *(const bf16x8*)&a_lds[r * 64 + chs * 8];
            }
            #pragma unroll
            for (int j = 0; j < 4; ++j) {
                int cl = c0w + 16 * j + (lane & 15);
                int chs = chread ^ 7 ^ (cl & 7);      // bg stored descending
                bfr[j] = *(const bf16x8*)&b_lds[cl * 64 + chs * 8];
            }
            #pragma unroll
            for (int i = 0; i < 4; ++i)
                #pragma unroll
                for (int j = 0; j < 4; ++j)
                    acc[i][j] = __builtin_amdgcn_mfma_f32_16x16x32_bf16(af[i], bfr[j], acc[i][j], 0, 0, 0);
        }
    }

    // epilogue: exp + col-mask + row reduce + atomics
    bool okc[4];
    #pragma unroll
    for (int j = 0; j < 4; ++j)
        okc[j] = (colbase + c0w + 16 * j + (lane & 15)) < nbgt;
    #pragma unroll
    for (int i = 0; i < 4; ++i) {
        #pragma unroll
        for (int reg = 0; reg < 4; ++reg) {
            float msum = 0.f;
            #pragma unroll
            for (int j = 0; j < 4; ++j) {
                float e = __expf(acc[i][j][reg] * TEMP_INV);
                msum += okc[j] ? e : 0.f;
            }
            msum += __shfl_xor(msum, 1);
            msum += __shfl_xor(msum, 2);
            msum += __shfl_xor(msum, 4);
            msum += __shfl_xor(msum, 8);
            if ((lane & 15) == 0) {
                int row = rowbase + r0w + 16 * i + quad * 4 + reg;
                if (row < nfgt) atomicAdd(&neg[t * N + row], msum);
            }
        }
    }
}

// ---------------------------------------------------------------------------
// Fused per-frame + final loss: 512 threads, wave t handles frame t.
// Visibility of sim's atomics is guaranteed by stream ordering (kernel
// boundary), NOT per-block fences.
__global__ void loss_kernel(const float* __restrict__ negbuf,
                            const float* __restrict__ posc,
                            const int* __restrict__ nfg,
                            const int* __restrict__ nbg,
                            float* __restrict__ out_loss) {
    int tid = threadIdx.x;
    int t = tid >> 6;
    int lane = tid & 63;
    int nfgt = nfg[t];
    float s = 0.f;
    #pragma unroll 4
    for (int k = lane; k < nfgt; k += 64) {
        float pos = __expf(posc[t * N + k] * TEMP_INV);
        float ng = negbuf[t * N + k];
        s += logf((pos + ng + EPS) / pos);
    }
    for (int o = 32; o > 0; o >>= 1) s += __shfl_down(s, o);
    __shared__ float fl[8], vv[8];
    if (lane == 0) {
        float valid = (nfgt > 0 && nbg[t] > 0) ? 1.f : 0.f;
        fl[t] = valid * (s / fmaxf((float)nfgt, 1.f));
        vv[t] = valid;
    }
    __syncthreads();
    if (tid == 0) {
        float ls = 0.f, v = 0.f;
        for (int i = 0; i < T; ++i) { ls += fl[i]; v += vv[i]; }
        out_loss[0] = (v > 0.f) ? ls / fmaxf(v, 1.f) : 0.f;
    }
}

// ---------------------------------------------------------------------------
extern "C" void kernel_launch(void* const* d_in, const int* in_sizes, int n_in,
                              void* d_out, int out_size, void* d_ws, size_t ws_size,
                              hipStream_t stream) {
    const float* cur  = (const float*)d_in[0];
    const float* hist = (const float*)d_in[1];
    const float* feat = (const float*)d_in[2];
    float* out = (float*)d_out;   // labels[32768] ++ loss[1]

    char* ws = (char*)d_ws;
    bf16*  fpack   = (bf16*)ws;                           // 8*4096*256 bf16 = 16 MiB
    size_t off = (size_t)T * N * C * sizeof(bf16);
    float* negbuf  = (float*)(ws + off);  off += (size_t)T * N * 4;
    float* posc    = (float*)(ws + off);  off += (size_t)T * N * 4;
    int*   nfg     = (int*)(ws + off);                    // nfg[8] nbg[8]
    int*   nbg     = nfg + 8;

    hipMemsetAsync(nfg, 0, 64, stream);                   // zero counters (capturable)
    normalize_kernel<<<1024, 256, 0, stream>>>(feat, cur, hist, out, negbuf, posc, fpack, nfg, nbg);
    sim_kernel<<<8192, 256, 0, stream>>>(fpack, nfg, nbg, negbuf);
    loss_kernel<<<1, 512, 0, stream>>>(negbuf, posc, nfg, nbg, out + 32768);
}